// Round 1
// baseline (296.955 us; speedup 1.0000x reference)
//
#include <hip/hip_runtime.h>
#include <hip/hip_bf16.h>
#include <cstdint>

// EdgeMLP: score = W3 @ sig(W2 @ sig(W1 @ [h1_u,h1_v,h2_u,h2_u] + b1) + b2) + b3
// Factored: z1 = Anode[src] + Bnode[dst], where
//   Anode[u] = b1 + W1a @ h1[u] + (W1c+W1d) @ h2[u]   (cols 0:64 and 128:256)
//   Bnode[v] = W1b @ h1[v]                            (cols 64:128)

__device__ __forceinline__ float sigmoidf_(float x) {
    return 1.0f / (1.0f + __expf(-x));
}

// ---------- prep: fold/transpose weights to k-major ----------
__global__ void prep_kernel(const float* __restrict__ W1, const float* __restrict__ W2,
                            float* __restrict__ WA, float* __restrict__ WB,
                            float* __restrict__ WCD, float* __restrict__ W2T) {
    int i = blockIdx.x * blockDim.x + threadIdx.x;
    if (i < 8192) {                      // WA/WB/WCD: [k=64][j=128]
        int k = i >> 7, j = i & 127;
        WA[i]  = W1[j * 256 + k];
        WB[i]  = W1[j * 256 + 64 + k];
        WCD[i] = W1[j * 256 + 128 + k] + W1[j * 256 + 192 + k];
    }
    if (i < 16384) {                     // W2T: [k=128][j=128]
        int k = i >> 7, j = i & 127;
        W2T[i] = W2[j * 128 + k];
    }
}

// ---------- node-side: Anode/Bnode = per-node layer-1 partials ----------
__global__ __launch_bounds__(256) void node_kernel(
    const float* __restrict__ h1, const float* __restrict__ h2,
    const float* __restrict__ WA, const float* __restrict__ WB,
    const float* __restrict__ WCD, const float* __restrict__ b1,
    float* __restrict__ Aout, float* __restrict__ Bout, int N)
{
    __shared__ float x1t[64 * 65];   // [k][node], stride 65
    __shared__ float x2t[64 * 65];
    const int tid = threadIdx.x;
    const int n0 = blockIdx.x * 64;

    #pragma unroll
    for (int i = 0; i < 16; ++i) {
        int local = i * 256 + tid;           // 0..4095
        int node = local >> 6, k = local & 63;
        bool ok = (n0 + node) < N;
        int g = n0 * 64 + local;
        x1t[k * 65 + node] = ok ? h1[g] : 0.0f;
        x2t[k * 65 + node] = ok ? h2[g] : 0.0f;
    }
    __syncthreads();

    const int ln = tid & 63;                              // lane = node
    const int j0 = __builtin_amdgcn_readfirstlane((tid >> 6) << 5);  // wave's j-chunk
    const bool valid = (n0 + ln) < N;

    float acc[32];
    // ---- A chunk: b1 + WA@h1 + WCD@h2 ----
    #pragma unroll
    for (int j = 0; j < 32; ++j) acc[j] = b1[j0 + j];
    for (int k = 0; k < 64; ++k) {
        float x1k = x1t[k * 65 + ln];
        const float* wa = WA + k * 128 + j0;
        #pragma unroll
        for (int j = 0; j < 32; ++j) acc[j] = fmaf(wa[j], x1k, acc[j]);
        float x2k = x2t[k * 65 + ln];
        const float* wc = WCD + k * 128 + j0;
        #pragma unroll
        for (int j = 0; j < 32; ++j) acc[j] = fmaf(wc[j], x2k, acc[j]);
    }
    if (valid) {
        float* dp = Aout + (size_t)(n0 + ln) * 128 + j0;
        #pragma unroll
        for (int q = 0; q < 8; ++q) {
            *(float4*)(dp + 4 * q) =
                make_float4(acc[4*q], acc[4*q+1], acc[4*q+2], acc[4*q+3]);
        }
    }
    // ---- B chunk: WB@h1 ----
    #pragma unroll
    for (int j = 0; j < 32; ++j) acc[j] = 0.0f;
    for (int k = 0; k < 64; ++k) {
        float x1k = x1t[k * 65 + ln];
        const float* wb = WB + k * 128 + j0;
        #pragma unroll
        for (int j = 0; j < 32; ++j) acc[j] = fmaf(wb[j], x1k, acc[j]);
    }
    if (valid) {
        float* dp = Bout + (size_t)(n0 + ln) * 128 + j0;
        #pragma unroll
        for (int q = 0; q < 8; ++q) {
            *(float4*)(dp + 4 * q) =
                make_float4(acc[4*q], acc[4*q+1], acc[4*q+2], acc[4*q+3]);
        }
    }
}

// ---------- edge-side: gather + sigmoid + layer2 + layer3 ----------
__global__ __launch_bounds__(256) void edge_kernel(
    const float* __restrict__ Am, const float* __restrict__ Bm,
    const int* __restrict__ src, const int* __restrict__ dst,
    const float* __restrict__ W2T, const float* __restrict__ b2,
    const float* __restrict__ W3, const float* __restrict__ b3,
    float* __restrict__ out, int E)
{
    __shared__ float h_tile[128 * 65];   // [k][edge], stride 65
    __shared__ float part[256];
    const int tid = threadIdx.x;
    const int w  = tid >> 6;
    const int ln = tid & 63;
    const int e0 = blockIdx.x * 64;

    // ---- phase 1: gather A[src]+B[dst], sigmoid, stage transposed ----
    {
        const int tt = ln & 15;
        const int ebase = e0 + (w << 4);   // wave w handles 16 edges
        int us = 0, vs = 0;
        if (ebase + tt < E) { us = src[ebase + tt]; vs = dst[ebase + tt]; }
        #pragma unroll 4
        for (int t = 0; t < 16; ++t) {
            if (ebase + t < E) {
                int u = __builtin_amdgcn_readlane(us, t);
                int v = __builtin_amdgcn_readlane(vs, t);
                const float2 av = *(const float2*)(Am + (size_t)u * 128 + (ln << 1));
                const float2 bv = *(const float2*)(Bm + (size_t)v * 128 + (ln << 1));
                float z0 = av.x + bv.x;
                float z1 = av.y + bv.y;
                int e = (w << 4) + t;
                h_tile[(ln * 2)     * 65 + e] = sigmoidf_(z0);
                h_tile[(ln * 2 + 1) * 65 + e] = sigmoidf_(z1);
            }
        }
    }
    __syncthreads();

    // ---- phase 2: layer-2 j-chunk per wave, lane = edge ----
    const int j0 = __builtin_amdgcn_readfirstlane((tid >> 6) << 5);
    float acc[32];
    #pragma unroll
    for (int j = 0; j < 32; ++j) acc[j] = b2[j0 + j];
    for (int k = 0; k < 128; ++k) {
        float hk = h_tile[k * 65 + ln];
        const float* wr = W2T + k * 128 + j0;
        #pragma unroll
        for (int j = 0; j < 32; ++j) acc[j] = fmaf(wr[j], hk, acc[j]);
    }
    // ---- layer 3 partial ----
    float sc = 0.0f;
    #pragma unroll
    for (int j = 0; j < 32; ++j) sc = fmaf(W3[j0 + j], sigmoidf_(acc[j]), sc);
    part[w * 64 + ln] = sc;
    __syncthreads();
    if (w == 0 && (e0 + ln) < E) {
        out[e0 + ln] = part[ln] + part[64 + ln] + part[128 + ln] + part[192 + ln] + b3[0];
    }
}

// ---------- fallback (only if workspace too small) ----------
__global__ void naive_kernel(
    const float* __restrict__ h1, const float* __restrict__ h2,
    const int* __restrict__ src, const int* __restrict__ dst,
    const float* __restrict__ W1, const float* __restrict__ b1,
    const float* __restrict__ W2, const float* __restrict__ b2,
    const float* __restrict__ W3, const float* __restrict__ b3,
    float* __restrict__ out, int E, int N)
{
    int e = blockIdx.x * blockDim.x + threadIdx.x;
    if (e >= E) return;
    int u = src[e], v = dst[e];
    float h[128];
    for (int j = 0; j < 128; ++j) {
        float z = b1[j];
        const float* wj = W1 + j * 256;
        for (int k = 0; k < 64; ++k) {
            z += wj[k] * h1[(size_t)u * 64 + k]
               + wj[64 + k] * h1[(size_t)v * 64 + k]
               + (wj[128 + k] + wj[192 + k]) * h2[(size_t)u * 64 + k];
        }
        h[j] = sigmoidf_(z);
    }
    float g[128];
    for (int j = 0; j < 128; ++j) {
        float z = b2[j];
        for (int k = 0; k < 128; ++k) z = fmaf(W2[j * 128 + k], h[k], z);
        g[j] = sigmoidf_(z);
    }
    float s = b3[0];
    for (int j = 0; j < 128; ++j) s = fmaf(W3[j], g[j], s);
    out[e] = s;
}

extern "C" void kernel_launch(void* const* d_in, const int* in_sizes, int n_in,
                              void* d_out, int out_size, void* d_ws, size_t ws_size,
                              hipStream_t stream) {
    const float* h1 = (const float*)d_in[0];
    const float* h2 = (const float*)d_in[1];
    const int*  src = (const int*)d_in[2];
    const int*  dst = (const int*)d_in[3];
    const float* W1 = (const float*)d_in[4];
    const float* b1 = (const float*)d_in[5];
    const float* W2 = (const float*)d_in[6];
    const float* b2 = (const float*)d_in[7];
    const float* W3 = (const float*)d_in[8];
    const float* b3 = (const float*)d_in[9];
    float* out = (float*)d_out;

    const int N = in_sizes[0] / 64;
    const int E = in_sizes[2];

    // workspace layout (floats)
    size_t offA   = 0;
    size_t offB   = offA + (size_t)N * 128;
    size_t offWA  = offB + (size_t)N * 128;
    size_t offWB  = offWA + 8192;
    size_t offWCD = offWB + 8192;
    size_t offW2T = offWCD + 8192;
    size_t totalF = offW2T + 16384;

    if (ws_size < totalF * sizeof(float)) {
        naive_kernel<<<(E + 255) / 256, 256, 0, stream>>>(
            h1, h2, src, dst, W1, b1, W2, b2, W3, b3, out, E, N);
        return;
    }

    float* ws = (float*)d_ws;
    prep_kernel<<<64, 256, 0, stream>>>(W1, W2, ws + offWA, ws + offWB,
                                        ws + offWCD, ws + offW2T);
    node_kernel<<<(N + 63) / 64, 256, 0, stream>>>(
        h1, h2, ws + offWA, ws + offWB, ws + offWCD, b1,
        ws + offA, ws + offB, N);
    edge_kernel<<<(E + 63) / 64, 256, 0, stream>>>(
        ws + offA, ws + offB, src, dst, ws + offW2T, b2, W3, b3, out, E);
}

// Round 2
// 217.805 us; speedup vs baseline: 1.3634x; 1.3634x over previous
//
#include <hip/hip_runtime.h>
#include <hip/hip_bf16.h>
#include <cstdint>

// EdgeMLP: score = W3 @ sig(W2 @ sig(W1 @ [h1_u,h1_v,h2_u,h2_u] + b1) + b2) + b3
// Factored: z1 = Anode[src] + Bnode[dst], where
//   Anode[u] = b1 + W1a @ h1[u] + (W1c+W1d) @ h2[u]   (cols 0:64 and 128:256)
//   Bnode[v] = W1b @ h1[v]                            (cols 64:128)
// Layer 2 runs on bf16 MFMA (16x16x32); layers 1/3 stay fp32.

typedef __attribute__((ext_vector_type(8))) short bf16x8;
typedef __attribute__((ext_vector_type(4))) float f32x4;

__device__ __forceinline__ float sigmoidf_(float x) {
    return 1.0f / (1.0f + __expf(-x));
}

__device__ __forceinline__ uint32_t packbf2(float a, float b) {
    uint32_t ua = __float_as_uint(a), ub = __float_as_uint(b);
    ua = (ua + 0x7fffu + ((ua >> 16) & 1u)) >> 16;       // RNE truncate
    ub = (ub + 0x7fffu + ((ub >> 16) & 1u)) >> 16;
    return ua | (ub << 16);
}

// ---------- prep: fold/transpose W1; W2 -> bf16 MFMA-B fragment layout ----------
// W2F flat index: ((kk*8 + nt)*64 + lane)*8 + j
//   n = nt*16 + (lane&15);  k = kk*32 + (lane>>4)*8 + j;  value = bf16(W2[n][k])
__global__ void prep_kernel(const float* __restrict__ W1, const float* __restrict__ W2,
                            float* __restrict__ WA, float* __restrict__ WB,
                            float* __restrict__ WCD, ushort* __restrict__ W2F) {
    int i = blockIdx.x * blockDim.x + threadIdx.x;
    if (i < 8192) {                      // WA/WB/WCD: [k=64][j=128]
        int k = i >> 7, j = i & 127;
        WA[i]  = W1[j * 256 + k];
        WB[i]  = W1[j * 256 + 64 + k];
        WCD[i] = W1[j * 256 + 128 + k] + W1[j * 256 + 192 + k];
    }
    if (i < 16384) {                     // W2F: bf16 MFMA B-frags
        int j  = i & 7;
        int lf = (i >> 3) & 63;
        int nt = (i >> 9) & 7;
        int kk = i >> 12;
        int n  = nt * 16 + (lf & 15);
        int kg = kk * 32 + (lf >> 4) * 8 + j;
        uint32_t u = __float_as_uint(W2[n * 128 + kg]);
        W2F[i] = (ushort)((u + 0x7fffu + ((u >> 16) & 1u)) >> 16);
    }
}

// ---------- node-side: Anode/Bnode = per-node layer-1 partials (fp32 VALU) ----------
__global__ __launch_bounds__(256) void node_kernel(
    const float* __restrict__ h1, const float* __restrict__ h2,
    const float* __restrict__ WA, const float* __restrict__ WB,
    const float* __restrict__ WCD, const float* __restrict__ b1,
    float* __restrict__ Aout, float* __restrict__ Bout, int N)
{
    __shared__ float x1t[64 * 65];   // [k][node], stride 65
    __shared__ float x2t[64 * 65];
    const int tid = threadIdx.x;
    const int n0 = blockIdx.x * 64;

    #pragma unroll
    for (int i = 0; i < 16; ++i) {
        int local = i * 256 + tid;           // 0..4095
        int node = local >> 6, k = local & 63;
        bool ok = (n0 + node) < N;
        int g = n0 * 64 + local;
        x1t[k * 65 + node] = ok ? h1[g] : 0.0f;
        x2t[k * 65 + node] = ok ? h2[g] : 0.0f;
    }
    __syncthreads();

    const int ln = tid & 63;                              // lane = node
    const int j0 = __builtin_amdgcn_readfirstlane((tid >> 6) << 5);  // wave's j-chunk
    const bool valid = (n0 + ln) < N;

    float acc[32];
    // ---- A chunk: b1 + WA@h1 + WCD@h2 ----
    #pragma unroll
    for (int j = 0; j < 32; ++j) acc[j] = b1[j0 + j];
    for (int k = 0; k < 64; ++k) {
        float x1k = x1t[k * 65 + ln];
        const float* wa = WA + k * 128 + j0;
        #pragma unroll
        for (int j = 0; j < 32; ++j) acc[j] = fmaf(wa[j], x1k, acc[j]);
        float x2k = x2t[k * 65 + ln];
        const float* wc = WCD + k * 128 + j0;
        #pragma unroll
        for (int j = 0; j < 32; ++j) acc[j] = fmaf(wc[j], x2k, acc[j]);
    }
    if (valid) {
        float* dp = Aout + (size_t)(n0 + ln) * 128 + j0;
        #pragma unroll
        for (int q = 0; q < 8; ++q) {
            *(float4*)(dp + 4 * q) =
                make_float4(acc[4*q], acc[4*q+1], acc[4*q+2], acc[4*q+3]);
        }
    }
    // ---- B chunk: WB@h1 ----
    #pragma unroll
    for (int j = 0; j < 32; ++j) acc[j] = 0.0f;
    for (int k = 0; k < 64; ++k) {
        float x1k = x1t[k * 65 + ln];
        const float* wb = WB + k * 128 + j0;
        #pragma unroll
        for (int j = 0; j < 32; ++j) acc[j] = fmaf(wb[j], x1k, acc[j]);
    }
    if (valid) {
        float* dp = Bout + (size_t)(n0 + ln) * 128 + j0;
        #pragma unroll
        for (int q = 0; q < 8; ++q) {
            *(float4*)(dp + 4 * q) =
                make_float4(acc[4*q], acc[4*q+1], acc[4*q+2], acc[4*q+3]);
        }
    }
}

// ---------- edge-side: gather + sigmoid + MFMA layer2 + fused layer3 ----------
__global__ __launch_bounds__(256) void edge_kernel(
    const float* __restrict__ Am, const float* __restrict__ Bm,
    const int* __restrict__ src, const int* __restrict__ dst,
    const ushort* __restrict__ W2F, const float* __restrict__ b2,
    const float* __restrict__ W3, const float* __restrict__ b3,
    float* __restrict__ out, int E)
{
    // h tile: [64 edges][136 bf16] — row stride 272 B (68 dwords) ->
    // ds_read_b128 A-frag reads land on distinct banks (floor rate).
    __shared__ __align__(16) ushort hlds[64 * 136];   // 17408 B
    __shared__ __align__(16) ushort w2f[16384];       // 32768 B: B-frags
    const int tid = threadIdx.x;
    const int g  = tid >> 6;          // wave id: owns edges g*16..g*16+15
    const int ln = tid & 63;
    const int e0 = blockIdx.x * 64;

    // ---- stage W2 fragments into LDS (32 KB, coalesced) ----
    #pragma unroll
    for (int i = 0; i < 8; ++i)
        ((float4*)w2f)[tid + i * 256] = ((const float4*)W2F)[tid + i * 256];

    // ---- phase 1: gather A[src]+B[dst], sigmoid, pack bf16 into LDS ----
    int us = 0, vs = 0;
    if (ln < 16 && (e0 + g * 16 + ln) < E) {
        us = src[e0 + g * 16 + ln];
        vs = dst[e0 + g * 16 + ln];
    }
    #pragma unroll
    for (int t = 0; t < 16; ++t) {
        if (e0 + g * 16 + t < E) {
            int u = __builtin_amdgcn_readlane(us, t);
            int v = __builtin_amdgcn_readlane(vs, t);
            const float2 av = *(const float2*)(Am + (size_t)u * 128 + (ln << 1));
            const float2 bv = *(const float2*)(Bm + (size_t)v * 128 + (ln << 1));
            uint32_t pk = packbf2(sigmoidf_(av.x + bv.x), sigmoidf_(av.y + bv.y));
            *(uint32_t*)&hlds[(g * 16 + t) * 136 + (ln << 1)] = pk;
        }
    }
    __syncthreads();

    // ---- phase 2: wave g computes M16 x N128 x K128 via 32 MFMAs ----
    f32x4 acc[8];
    #pragma unroll
    for (int i = 0; i < 8; ++i)
        #pragma unroll
        for (int r = 0; r < 4; ++r) acc[i][r] = 0.0f;

    const ushort* arow = &hlds[(g * 16 + (ln & 15)) * 136 + (ln >> 4) * 8];
    const ushort* brow = &w2f[ln * 8];
    #pragma unroll
    for (int kk = 0; kk < 4; ++kk) {
        bf16x8 a = *(const bf16x8*)(arow + kk * 32);
        #pragma unroll
        for (int nt = 0; nt < 8; ++nt) {
            bf16x8 b = *(const bf16x8*)(brow + (kk * 8 + nt) * 512);
            acc[nt] = __builtin_amdgcn_mfma_f32_16x16x32_bf16(a, b, acc[nt], 0, 0, 0);
        }
    }

    // ---- epilogue: +b2, sigmoid, dot W3, reduce over the 16 lanes per quad ----
    // C/D layout: edge = g*16 + (ln>>4)*4 + r, col n = nt*16 + (ln&15)
    float p[4] = {0.f, 0.f, 0.f, 0.f};
    const int nl = ln & 15;
    #pragma unroll
    for (int nt = 0; nt < 8; ++nt) {
        int n = nt * 16 + nl;
        float b2n = b2[n], w3n = W3[n];
        #pragma unroll
        for (int r = 0; r < 4; ++r) {
            float h3 = sigmoidf_(acc[nt][r] + b2n);
            p[r] = fmaf(w3n, h3, p[r]);
        }
    }
    #pragma unroll
    for (int r = 0; r < 4; ++r) {
        p[r] += __shfl_xor(p[r], 1, 16);
        p[r] += __shfl_xor(p[r], 2, 16);
        p[r] += __shfl_xor(p[r], 4, 16);
        p[r] += __shfl_xor(p[r], 8, 16);
    }
    if (nl == 0) {
        const float b3c = b3[0];
        int ebase = e0 + g * 16 + (ln >> 4) * 4;
        #pragma unroll
        for (int r = 0; r < 4; ++r)
            if (ebase + r < E) out[ebase + r] = p[r] + b3c;
    }
}

// ---------- fallback (only if workspace too small) ----------
__global__ void naive_kernel(
    const float* __restrict__ h1, const float* __restrict__ h2,
    const int* __restrict__ src, const int* __restrict__ dst,
    const float* __restrict__ W1, const float* __restrict__ b1,
    const float* __restrict__ W2, const float* __restrict__ b2,
    const float* __restrict__ W3, const float* __restrict__ b3,
    float* __restrict__ out, int E, int N)
{
    int e = blockIdx.x * blockDim.x + threadIdx.x;
    if (e >= E) return;
    int u = src[e], v = dst[e];
    float h[128];
    for (int j = 0; j < 128; ++j) {
        float z = b1[j];
        const float* wj = W1 + j * 256;
        for (int k = 0; k < 64; ++k) {
            z += wj[k] * h1[(size_t)u * 64 + k]
               + wj[64 + k] * h1[(size_t)v * 64 + k]
               + (wj[128 + k] + wj[192 + k]) * h2[(size_t)u * 64 + k];
        }
        h[j] = sigmoidf_(z);
    }
    float gg[128];
    for (int j = 0; j < 128; ++j) {
        float z = b2[j];
        for (int k = 0; k < 128; ++k) z = fmaf(W2[j * 128 + k], h[k], z);
        gg[j] = sigmoidf_(z);
    }
    float s = b3[0];
    for (int j = 0; j < 128; ++j) s = fmaf(W3[j], gg[j], s);
    out[e] = s;
}

extern "C" void kernel_launch(void* const* d_in, const int* in_sizes, int n_in,
                              void* d_out, int out_size, void* d_ws, size_t ws_size,
                              hipStream_t stream) {
    const float* h1 = (const float*)d_in[0];
    const float* h2 = (const float*)d_in[1];
    const int*  src = (const int*)d_in[2];
    const int*  dst = (const int*)d_in[3];
    const float* W1 = (const float*)d_in[4];
    const float* b1 = (const float*)d_in[5];
    const float* W2 = (const float*)d_in[6];
    const float* b2 = (const float*)d_in[7];
    const float* W3 = (const float*)d_in[8];
    const float* b3 = (const float*)d_in[9];
    float* out = (float*)d_out;

    const int N = in_sizes[0] / 64;
    const int E = in_sizes[2];

    // workspace layout (float units; all offsets 16B-aligned)
    size_t offA   = 0;
    size_t offB   = offA + (size_t)N * 128;
    size_t offWA  = offB + (size_t)N * 128;
    size_t offWB  = offWA + 8192;
    size_t offWCD = offWB + 8192;
    size_t offW2F = offWCD + 8192;            // 16384 ushorts = 8192 floats
    size_t totalF = offW2F + 8192;

    if (ws_size < totalF * sizeof(float)) {
        naive_kernel<<<(E + 255) / 256, 256, 0, stream>>>(
            h1, h2, src, dst, W1, b1, W2, b2, W3, b3, out, E, N);
        return;
    }

    float* ws = (float*)d_ws;
    prep_kernel<<<64, 256, 0, stream>>>(W1, W2, ws + offWA, ws + offWB,
                                        ws + offWCD, (ushort*)(ws + offW2F));
    node_kernel<<<(N + 63) / 64, 256, 0, stream>>>(
        h1, h2, ws + offWA, ws + offWB, ws + offWCD, b1,
        ws + offA, ws + offB, N);
    edge_kernel<<<(E + 63) / 64, 256, 0, stream>>>(
        ws + offA, ws + offB, src, dst, (const ushort*)(ws + offW2F),
        b2, W3, b3, out, E);
}